// Round 7
// baseline (631.827 us; speedup 1.0000x reference)
//
#include <hip/hip_runtime.h>
#include <math.h>

#define DIM 768
#define HEADS 12
#define DH 64
#define NSEQ 4096
#define BATCH 2
#define BH (BATCH * HEADS)

typedef __attribute__((ext_vector_type(8))) short bf16x8;
typedef __attribute__((ext_vector_type(4))) short short4v;
typedef __attribute__((ext_vector_type(4))) float f32x4;

// round-half-up bf16: <=0.5 ULP, 2 VALU ops
__device__ __forceinline__ unsigned short f2bf(float x) {
  return (unsigned short)((__float_as_uint(x) + 0x8000u) >> 16);
}

// ---------------------------------------------------------------------------
// fp32 -> bf16 elementwise (x). 8 elems/thread.
// ---------------------------------------------------------------------------
__global__ __launch_bounds__(256) void cvt_bf16(const float* __restrict__ in,
                                                unsigned short* __restrict__ out,
                                                int n) {
  int i = (blockIdx.x * 256 + threadIdx.x) * 8;
  if (i >= n) return;
  float4 a = *(const float4*)(in + i);
  float4 b = *(const float4*)(in + i + 4);
  ushort4 v0, v1;
  v0.x = f2bf(a.x); v0.y = f2bf(a.y); v0.z = f2bf(a.z); v0.w = f2bf(a.w);
  v1.x = f2bf(b.x); v1.y = f2bf(b.y); v1.z = f2bf(b.z); v1.w = f2bf(b.w);
  *(ushort4*)(out + i) = v0;
  *(ushort4*)(out + i + 4) = v1;
}

// ---------------------------------------------------------------------------
// Transpose + convert: in [K][N] fp32 -> out [N][K] bf16. 32x32 tiles.
// ---------------------------------------------------------------------------
__global__ __launch_bounds__(256) void transpose_cvt(const float* __restrict__ in,
                                                     unsigned short* __restrict__ out,
                                                     int K, int N) {
  __shared__ unsigned short s[32][34];
  int t = threadIdx.x;
  int tx = t & 31, ty = t >> 5;
  int n0 = blockIdx.x * 32, k0 = blockIdx.y * 32;
#pragma unroll
  for (int i = 0; i < 4; ++i) {
    int r = ty + i * 8;
    s[r][tx] = f2bf(in[(size_t)(k0 + r) * N + n0 + tx]);
  }
  __syncthreads();
#pragma unroll
  for (int i = 0; i < 4; ++i) {
    int r = ty + i * 8;
    out[(size_t)(n0 + r) * K + k0 + tx] = s[tx][r];
  }
}

// ---------------------------------------------------------------------------
// V [bh][n][64] -> Vt [bh][64][n], bf16, 64x64 LDS tiles.
// ---------------------------------------------------------------------------
__global__ __launch_bounds__(256) void vtrans(const unsigned short* __restrict__ Vb,
                                              unsigned short* __restrict__ Vt) {
  __shared__ unsigned short s[64][72];
  int t = threadIdx.x;
  int bh = blockIdx.y;
  int n0 = blockIdx.x * 64;
  const unsigned short* src = Vb + ((size_t)bh * NSEQ + n0) * DH;
#pragma unroll
  for (int i = 0; i < 2; ++i) {
    int idx = t + i * 256;
    int row = idx >> 3, ch = (idx & 7) * 8;
    *(uint4*)&s[row][ch] = *(const uint4*)(src + (size_t)row * DH + ch);
  }
  __syncthreads();
  unsigned short* dst = Vt + (size_t)bh * DH * NSEQ + n0;
#pragma unroll
  for (int i = 0; i < 2; ++i) {
    int idx = t + i * 256;
    int dh = idx >> 3, ch = (idx & 7) * 8;
    unsigned short tmp[8];
#pragma unroll
    for (int j = 0; j < 8; ++j) tmp[j] = s[ch + j][dh];
    *(uint4*)&dst[(size_t)dh * NSEQ + ch] = *(uint4*)tmp;
  }
}

// ---------------------------------------------------------------------------
// bf16 MFMA GEMM: C[M,N] = A[M,K] @ Bt[N,K]^T + bias. (unchanged from R6)
// ---------------------------------------------------------------------------
template <int TM>
__global__ __launch_bounds__(256) void gemm_bt(
    const unsigned short* __restrict__ A, const unsigned short* __restrict__ Bt,
    const float* __restrict__ bias, float* __restrict__ outf,
    unsigned short* __restrict__ Qb, unsigned short* __restrict__ Kb,
    unsigned short* __restrict__ V0, int M, int N, int K, int mode) {
  __shared__ unsigned short As[TM * 72];
  __shared__ unsigned short Bs[128 * 72];  // reused as fp32 C-scratch in epilogue
  constexpr int MI = TM / 32;
  const int t = threadIdx.x;
  const int wave = t >> 6, lane = t & 63;
  const int ln16 = lane & 15, quad = lane >> 4;
  const int rb = blockIdx.y, cb = blockIdx.x;
  const int rw = (wave >> 1) * (TM / 2);
  const int cw = (wave & 1) * 64;

  const int srow = lane >> 3;
  const int scol = (lane & 7) * 8;

  const unsigned short* gA = A + (size_t)(rb * TM + wave * (TM / 4) + srow) * K + scol;
  const unsigned short* gB = Bt + (size_t)(cb * 128 + wave * 32 + srow) * K + scol;

  f32x4 acc[MI][4];
#pragma unroll
  for (int i = 0; i < MI; ++i)
#pragma unroll
    for (int j = 0; j < 4; ++j) acc[i][j] = (f32x4){0.f, 0.f, 0.f, 0.f};

  uint4 av[MI], bv[4];
#pragma unroll
  for (int i = 0; i < MI; ++i) av[i] = *(const uint4*)(gA + (size_t)i * 8 * K);
#pragma unroll
  for (int i = 0; i < 4; ++i) bv[i] = *(const uint4*)(gB + (size_t)i * 8 * K);

  for (int k0 = 0; k0 < K; k0 += 64) {
    __syncthreads();
#pragma unroll
    for (int i = 0; i < MI; ++i)
      *(uint4*)&As[(wave * (TM / 4) + i * 8 + srow) * 72 + scol] = av[i];
#pragma unroll
    for (int i = 0; i < 4; ++i)
      *(uint4*)&Bs[(wave * 32 + i * 8 + srow) * 72 + scol] = bv[i];
    __syncthreads();
    if (k0 + 64 < K) {
#pragma unroll
      for (int i = 0; i < MI; ++i)
        av[i] = *(const uint4*)(gA + (size_t)i * 8 * K + k0 + 64);
#pragma unroll
      for (int i = 0; i < 4; ++i)
        bv[i] = *(const uint4*)(gB + (size_t)i * 8 * K + k0 + 64);
    }
#pragma unroll
    for (int kh = 0; kh < 2; ++kh) {
      bf16x8 a[MI], b[4];
#pragma unroll
      for (int mi = 0; mi < MI; ++mi)
        a[mi] = *(const bf16x8*)&As[(rw + mi * 16 + ln16) * 72 + kh * 32 + quad * 8];
#pragma unroll
      for (int ni = 0; ni < 4; ++ni)
        b[ni] = *(const bf16x8*)&Bs[(cw + ni * 16 + ln16) * 72 + kh * 32 + quad * 8];
#pragma unroll
      for (int mi = 0; mi < MI; ++mi)
#pragma unroll
        for (int ni = 0; ni < 4; ++ni)
          acc[mi][ni] = __builtin_amdgcn_mfma_f32_16x16x32_bf16(a[mi], b[ni],
                                                                acc[mi][ni], 0, 0, 0);
    }
  }

  if (mode == 0) {
    __syncthreads();
    const float scale = 0.036084391824351615f;  // 768^-0.5
    int col0abs = cb * 128 + cw;
    int which = (col0abs >= 2 * DIM) ? 2 : ((col0abs >= DIM) ? 1 : 0);
    int h = (col0abs - which * DIM) >> 6;
    unsigned short* dstp = (which == 0) ? Qb : ((which == 1) ? Kb : V0);
    const float mul = (which == 0) ? scale : 1.f;
    float* Cs = (float*)Bs + wave * (16 * 68);
    float bvv[4];
#pragma unroll
    for (int ni = 0; ni < 4; ++ni) bvv[ni] = bias[col0abs + ni * 16 + ln16];
#pragma unroll
    for (int mi = 0; mi < MI; ++mi) {
#pragma unroll
      for (int ni = 0; ni < 4; ++ni)
#pragma unroll
        for (int r = 0; r < 4; ++r)
          Cs[(quad * 4 + r) * 68 + ni * 16 + ln16] = (acc[mi][ni][r] + bvv[ni]) * mul;
      __asm__ volatile("s_waitcnt lgkmcnt(0)" ::: "memory");
      int token = rb * TM + rw + mi * 16 + ln16;
      int bb = token >> 12, nn = token & (NSEQ - 1);
      const float* src = &Cs[ln16 * 68 + quad * 16];
      float4 c0 = *(const float4*)(src + 0);
      float4 c1 = *(const float4*)(src + 4);
      float4 c2 = *(const float4*)(src + 8);
      float4 c3 = *(const float4*)(src + 12);
      unsigned short tmp[16];
      tmp[0] = f2bf(c0.x);  tmp[1] = f2bf(c0.y);  tmp[2] = f2bf(c0.z);  tmp[3] = f2bf(c0.w);
      tmp[4] = f2bf(c1.x);  tmp[5] = f2bf(c1.y);  tmp[6] = f2bf(c1.z);  tmp[7] = f2bf(c1.w);
      tmp[8] = f2bf(c2.x);  tmp[9] = f2bf(c2.y);  tmp[10] = f2bf(c2.z); tmp[11] = f2bf(c2.w);
      tmp[12] = f2bf(c3.x); tmp[13] = f2bf(c3.y); tmp[14] = f2bf(c3.z); tmp[15] = f2bf(c3.w);
      unsigned short* dp =
          dstp + ((size_t)(bb * HEADS + h) * NSEQ + nn) * DH + quad * 16;
      *(uint4*)&dp[0] = *(uint4*)&tmp[0];
      *(uint4*)&dp[8] = *(uint4*)&tmp[8];
      __asm__ volatile("s_waitcnt lgkmcnt(0)" ::: "memory");
    }
  } else {
#pragma unroll
    for (int ni = 0; ni < 4; ++ni) {
      int col = cb * 128 + cw + ni * 16 + ln16;
      float bv2 = bias[col];
#pragma unroll
      for (int mi = 0; mi < MI; ++mi)
#pragma unroll
        for (int r = 0; r < 4; ++r) {
          int token = rb * TM + rw + mi * 16 + quad * 4 + r;
          outf[(size_t)token * N + col] = acc[mi][ni][r] + bv2;
        }
    }
  }
}

// ---------------------------------------------------------------------------
// Register-P MFMA flash attention. 64 q/block, 4 waves; wave w owns keys
// w*16..w*16+15 of each staged 64-key tile. Compute S^T = K.Q^T (C-layout:
// row=key=quad*4+reg, col=q=ln16) -> exp in regs -> feed DIRECTLY as
// B-operand of mfma_f32_16x16x16bf16_1k (B[n=ln16][k=quad*4+j] == C-layout).
// P never touches LDS. O^T partials per wave; 4-phase LDS reduction at end
// (Ored aliases the staging buffer). No-max softmax; denominator = register
// partial sums (exact fp32).
// ---------------------------------------------------------------------------
__global__ __launch_bounds__(256) void attn_regp(
    const unsigned short* __restrict__ Qg, const unsigned short* __restrict__ Kg,
    const unsigned short* __restrict__ Vtg, unsigned short* __restrict__ ctxb) {
  __shared__ __align__(16) unsigned short pool[2 * 64 * 68];  // 17408 B
  unsigned short(*Ks)[68] = (unsigned short(*)[68])pool;          // [key][dh]
  unsigned short(*Vts)[68] = (unsigned short(*)[68])(pool + 64 * 68);  // [dh][key]
  float(*Ored)[68] = (float(*)[68])pool;  // aliases staging; used after loop

  int t = threadIdx.x;
  int wave = t >> 6, lane = t & 63;
  int ln16 = lane & 15, quad = lane >> 4;
  int bh = blockIdx.y;
  int q0 = blockIdx.x * 64;

  // Q as persistent B-frags: B[n=q=ln16][k=quad*8+j], 4 q-tiles x 2 k-halves
  bf16x8 qf[4][2];
#pragma unroll
  for (int qt = 0; qt < 4; ++qt)
#pragma unroll
    for (int kh = 0; kh < 2; ++kh)
      qf[qt][kh] = *(const bf16x8*)(Qg + ((size_t)bh * NSEQ + q0 + qt * 16 + ln16) * DH +
                                    kh * 32 + quad * 8);

  f32x4 O[4][4];  // O^T C-frags: [dh-tile mt][q-tile qt], row=dh=quad*4+reg, col=q=ln16
#pragma unroll
  for (int mt = 0; mt < 4; ++mt)
#pragma unroll
    for (int qt = 0; qt < 4; ++qt) O[mt][qt] = (f32x4){0.f, 0.f, 0.f, 0.f};
  float ladd[4] = {0.f, 0.f, 0.f, 0.f};

  const unsigned short* Kbase = Kg + (size_t)bh * NSEQ * DH;
  const unsigned short* Vbase = Vtg + (size_t)bh * DH * NSEQ;
  int srow = t >> 2, scol = (t & 3) << 4;

  uint4 kv0 = *(const uint4*)(Kbase + (size_t)srow * DH + scol);
  uint4 kv1 = *(const uint4*)(Kbase + (size_t)srow * DH + scol + 8);
  uint4 vv0 = *(const uint4*)(Vbase + (size_t)srow * NSEQ + scol);
  uint4 vv1 = *(const uint4*)(Vbase + (size_t)srow * NSEQ + scol + 8);

  for (int k0 = 0; k0 < NSEQ; k0 += 64) {
    __syncthreads();  // previous tile fully consumed
    *(uint4*)&Ks[srow][scol] = kv0;
    *(uint4*)&Ks[srow][scol + 8] = kv1;
    *(uint4*)&Vts[srow][scol] = vv0;
    *(uint4*)&Vts[srow][scol + 8] = vv1;
    __syncthreads();
    if (k0 + 64 < NSEQ) {  // prefetch next tile during compute
      kv0 = *(const uint4*)(Kbase + (size_t)(k0 + 64 + srow) * DH + scol);
      kv1 = *(const uint4*)(Kbase + (size_t)(k0 + 64 + srow) * DH + scol + 8);
      vv0 = *(const uint4*)(Vbase + (size_t)srow * NSEQ + k0 + 64 + scol);
      vv1 = *(const uint4*)(Vbase + (size_t)srow * NSEQ + k0 + 64 + scol + 8);
    }

    // S^T = K.Q^T for this wave's 16 keys: A = K-frags (m=key)
    bf16x8 ak0 = *(const bf16x8*)&Ks[wave * 16 + ln16][quad * 8];
    bf16x8 ak1 = *(const bf16x8*)&Ks[wave * 16 + ln16][32 + quad * 8];
    f32x4 S[4];
#pragma unroll
    for (int qt = 0; qt < 4; ++qt) {
      f32x4 s = (f32x4){0.f, 0.f, 0.f, 0.f};
      s = __builtin_amdgcn_mfma_f32_16x16x32_bf16(ak0, qf[qt][0], s, 0, 0, 0);
      s = __builtin_amdgcn_mfma_f32_16x16x32_bf16(ak1, qf[qt][1], s, 0, 0, 0);
      S[qt] = s;
    }

    // P^T = exp(S^T) in registers; pack straight into PV B-frags
    short4v pb[4];
#pragma unroll
    for (int qt = 0; qt < 4; ++qt) {
      float p0 = __expf(S[qt][0]);
      float p1 = __expf(S[qt][1]);
      float p2 = __expf(S[qt][2]);
      float p3 = __expf(S[qt][3]);
      ladd[qt] += (p0 + p1) + (p2 + p3);
      short4v pk;
      pk.x = (short)f2bf(p0); pk.y = (short)f2bf(p1);
      pk.z = (short)f2bf(p2); pk.w = (short)f2bf(p3);
      pb[qt] = pk;
    }

    // O^T += V^T . P^T : A = V^T frags (m=dh), k = this wave's 16 keys
#pragma unroll
    for (int mt = 0; mt < 4; ++mt) {
      short4v avf = *(const short4v*)&Vts[mt * 16 + ln16][wave * 16 + quad * 4];
#pragma unroll
      for (int qt = 0; qt < 4; ++qt)
        O[mt][qt] = __builtin_amdgcn_mfma_f32_16x16x16bf16_1k(avf, pb[qt], O[mt][qt], 0, 0, 0);
    }
  }

  // denominator: reduce over quads in-register (keys of this wave)
  float lq[4];
#pragma unroll
  for (int qt = 0; qt < 4; ++qt) {
    float v = ladd[qt];
    v += __shfl_xor(v, 16);
    v += __shfl_xor(v, 32);
    lq[qt] = v;
  }

  // cross-wave reduction in LDS (Ored aliases staging; barrier-separated)
  for (int w = 0; w < 4; ++w) {
    __syncthreads();
    if (wave == w) {
#pragma unroll
      for (int mt = 0; mt < 4; ++mt)
#pragma unroll
        for (int qt = 0; qt < 4; ++qt)
#pragma unroll
          for (int r = 0; r < 4; ++r) {
            float* p = &Ored[qt * 16 + ln16][mt * 16 + quad * 4 + r];
            *p = (w == 0) ? O[mt][qt][r] : (*p + O[mt][qt][r]);
          }
      if (quad == 0) {
#pragma unroll
        for (int qt = 0; qt < 4; ++qt) {
          float* p = &Ored[qt * 16 + ln16][64];
          *p = (w == 0) ? lq[qt] : (*p + lq[qt]);
        }
      }
    }
  }
  __syncthreads();

  // epilogue: thread t -> q = t>>2, dh-chunk = (t&3)*16; normalize, bf16 store
  int q = t >> 2, c = (t & 3) * 16;
  float inv = 1.f / Ored[q][64];
  unsigned short tmp[16];
#pragma unroll
  for (int j = 0; j < 16; ++j) tmp[j] = f2bf(Ored[q][c + j] * inv);
  int bb = bh / HEADS, h = bh % HEADS;
  unsigned short* op = ctxb + ((size_t)(bb * NSEQ + q0 + q)) * DIM + h * DH + c;
  *(uint4*)&op[0] = *(uint4*)&tmp[0];
  *(uint4*)&op[8] = *(uint4*)&tmp[8];
}

// ---------------------------------------------------------------------------
extern "C" void kernel_launch(void* const* d_in, const int* in_sizes, int n_in,
                              void* d_out, int out_size, void* d_ws, size_t ws_size,
                              hipStream_t stream) {
  const float* x = (const float*)d_in[0];
  const float* w_qkv = (const float*)d_in[1];
  const float* b_qkv = (const float*)d_in[2];
  const float* w_out = (const float*)d_in[3];
  const float* b_out = (const float*)d_in[4];
  float* out = (float*)d_out;

  const size_t plane = (size_t)BH * NSEQ * DH;  // 6,291,456
  unsigned short* xb = (unsigned short*)d_ws;            // [8192][768]
  unsigned short* wqkvT = xb + plane;                    // [2304][768]
  unsigned short* woutT = wqkvT + (size_t)3 * DIM * DIM; // [768][768]
  unsigned short* Qb = woutT + (size_t)DIM * DIM;        // [bh][n][64]
  unsigned short* Kb = Qb + plane;                       // [bh][n][64]
  unsigned short* V0 = Kb + plane;                       // [bh][n][64]
  unsigned short* Vtb = V0 + plane;                      // [bh][64][n]
  unsigned short* ctxb = Vtb + plane;                    // [8192][768]

  cvt_bf16<<<dim3((int)(plane / 2048)), 256, 0, stream>>>(x, xb, (int)plane);
  transpose_cvt<<<dim3(3 * DIM / 32, DIM / 32), 256, 0, stream>>>(w_qkv, wqkvT, DIM, 3 * DIM);
  transpose_cvt<<<dim3(DIM / 32, DIM / 32), 256, 0, stream>>>(w_out, woutT, DIM, DIM);

  gemm_bt<128><<<dim3(3 * DIM / 128, BATCH * NSEQ / 128), 256, 0, stream>>>(
      xb, wqkvT, b_qkv, nullptr, Qb, Kb, V0, BATCH * NSEQ, 3 * DIM, DIM, 0);

  vtrans<<<dim3(NSEQ / 64, BH), 256, 0, stream>>>(V0, Vtb);

  attn_regp<<<dim3(NSEQ / 64, BH), 256, 0, stream>>>(Qb, Kb, Vtb, ctxb);

  gemm_bt<64><<<dim3(DIM / 128, BATCH * NSEQ / 64), 256, 0, stream>>>(
      ctxb, woutT, b_out, out, nullptr, nullptr, nullptr, BATCH * NSEQ, DIM, DIM, 1);
}

// Round 8
// 488.803 us; speedup vs baseline: 1.2926x; 1.2926x over previous
//
#include <hip/hip_runtime.h>
#include <math.h>

#define DIM 768
#define HEADS 12
#define DH 64
#define NSEQ 4096
#define BATCH 2
#define BH (BATCH * HEADS)

typedef __attribute__((ext_vector_type(8))) short bf16x8;
typedef __attribute__((ext_vector_type(4))) float f32x4;

// round-half-up bf16: <=0.5 ULP, 2 VALU ops
__device__ __forceinline__ unsigned short f2bf(float x) {
  return (unsigned short)((__float_as_uint(x) + 0x8000u) >> 16);
}

// ---------------------------------------------------------------------------
// fp32 -> bf16 elementwise (x). 8 elems/thread.
// ---------------------------------------------------------------------------
__global__ __launch_bounds__(256) void cvt_bf16(const float* __restrict__ in,
                                                unsigned short* __restrict__ out,
                                                int n) {
  int i = (blockIdx.x * 256 + threadIdx.x) * 8;
  if (i >= n) return;
  float4 a = *(const float4*)(in + i);
  float4 b = *(const float4*)(in + i + 4);
  ushort4 v0, v1;
  v0.x = f2bf(a.x); v0.y = f2bf(a.y); v0.z = f2bf(a.z); v0.w = f2bf(a.w);
  v1.x = f2bf(b.x); v1.y = f2bf(b.y); v1.z = f2bf(b.z); v1.w = f2bf(b.w);
  *(ushort4*)(out + i) = v0;
  *(ushort4*)(out + i + 4) = v1;
}

// ---------------------------------------------------------------------------
// Transpose + convert: in [K][N] fp32 -> out [N][K] bf16. 32x32 tiles.
// ---------------------------------------------------------------------------
__global__ __launch_bounds__(256) void transpose_cvt(const float* __restrict__ in,
                                                     unsigned short* __restrict__ out,
                                                     int K, int N) {
  __shared__ unsigned short s[32][34];
  int t = threadIdx.x;
  int tx = t & 31, ty = t >> 5;
  int n0 = blockIdx.x * 32, k0 = blockIdx.y * 32;
#pragma unroll
  for (int i = 0; i < 4; ++i) {
    int r = ty + i * 8;
    s[r][tx] = f2bf(in[(size_t)(k0 + r) * N + n0 + tx]);
  }
  __syncthreads();
#pragma unroll
  for (int i = 0; i < 4; ++i) {
    int r = ty + i * 8;
    out[(size_t)(n0 + r) * K + k0 + tx] = s[tx][r];
  }
}

// ---------------------------------------------------------------------------
// V [bh][n][64] -> Vt [bh][64][n], bf16, 64x64 LDS tiles.
// ---------------------------------------------------------------------------
__global__ __launch_bounds__(256) void vtrans(const unsigned short* __restrict__ Vb,
                                              unsigned short* __restrict__ Vt) {
  __shared__ unsigned short s[64][72];
  int t = threadIdx.x;
  int bh = blockIdx.y;
  int n0 = blockIdx.x * 64;
  const unsigned short* src = Vb + ((size_t)bh * NSEQ + n0) * DH;
#pragma unroll
  for (int i = 0; i < 2; ++i) {
    int idx = t + i * 256;
    int row = idx >> 3, ch = (idx & 7) * 8;
    *(uint4*)&s[row][ch] = *(const uint4*)(src + (size_t)row * DH + ch);
  }
  __syncthreads();
  unsigned short* dst = Vt + (size_t)bh * DH * NSEQ + n0;
#pragma unroll
  for (int i = 0; i < 2; ++i) {
    int idx = t + i * 256;
    int dh = idx >> 3, ch = (idx & 7) * 8;
    unsigned short tmp[8];
#pragma unroll
    for (int j = 0; j < 8; ++j) tmp[j] = s[ch + j][dh];
    *(uint4*)&dst[(size_t)dh * NSEQ + ch] = *(uint4*)tmp;
  }
}

// ---------------------------------------------------------------------------
// bf16 MFMA GEMM: C[M,N] = A[M,K] @ Bt[N,K]^T + bias.
// TM x 128 tile, BK=64, 256 thr (4 waves, 2x2), 2-DEEP register pipeline:
// two staging sets; loads issued 2 iterations ahead of consumption so each
// has ~2 compute+barrier intervals to cover HBM latency. K must be a
// multiple of 128 (768 here).
// mode 0 (QKV): LDS-roundtrip epilogue -> Qb (scaled)/Kb/V0 [bh][n][64] bf16.
// mode 1: LDS-roundtrip epilogue -> fp32 row-major, 64 B/lane stores.
// ---------------------------------------------------------------------------
template <int TM>
__global__ __launch_bounds__(256) void gemm_bt2(
    const unsigned short* __restrict__ A, const unsigned short* __restrict__ Bt,
    const float* __restrict__ bias, float* __restrict__ outf,
    unsigned short* __restrict__ Qb, unsigned short* __restrict__ Kb,
    unsigned short* __restrict__ V0, int M, int N, int K, int mode) {
  __shared__ unsigned short As[TM * 72];
  __shared__ unsigned short Bs[128 * 72];  // reused as fp32 C-scratch in epilogue
  constexpr int MI = TM / 32;
  const int t = threadIdx.x;
  const int wave = t >> 6, lane = t & 63;
  const int ln16 = lane & 15, quad = lane >> 4;
  const int rb = blockIdx.y, cb = blockIdx.x;
  const int rw = (wave >> 1) * (TM / 2);
  const int cw = (wave & 1) * 64;

  const int srow = lane >> 3;
  const int scol = (lane & 7) * 8;

  const unsigned short* gA = A + (size_t)(rb * TM + wave * (TM / 4) + srow) * K + scol;
  const unsigned short* gB = Bt + (size_t)(cb * 128 + wave * 32 + srow) * K + scol;

  f32x4 acc[MI][4];
#pragma unroll
  for (int i = 0; i < MI; ++i)
#pragma unroll
    for (int j = 0; j < 4; ++j) acc[i][j] = (f32x4){0.f, 0.f, 0.f, 0.f};

  uint4 a0[MI], b0[4], a1[MI], b1[4];
#pragma unroll
  for (int i = 0; i < MI; ++i) a0[i] = *(const uint4*)(gA + (size_t)i * 8 * K);
#pragma unroll
  for (int i = 0; i < 4; ++i) b0[i] = *(const uint4*)(gB + (size_t)i * 8 * K);
#pragma unroll
  for (int i = 0; i < MI; ++i) a1[i] = *(const uint4*)(gA + (size_t)i * 8 * K + 64);
#pragma unroll
  for (int i = 0; i < 4; ++i) b1[i] = *(const uint4*)(gB + (size_t)i * 8 * K + 64);

  auto compute = [&]() {
#pragma unroll
    for (int kh = 0; kh < 2; ++kh) {
      bf16x8 a[MI], b[4];
#pragma unroll
      for (int mi = 0; mi < MI; ++mi)
        a[mi] = *(const bf16x8*)&As[(rw + mi * 16 + ln16) * 72 + kh * 32 + quad * 8];
#pragma unroll
      for (int ni = 0; ni < 4; ++ni)
        b[ni] = *(const bf16x8*)&Bs[(cw + ni * 16 + ln16) * 72 + kh * 32 + quad * 8];
#pragma unroll
      for (int mi = 0; mi < MI; ++mi)
#pragma unroll
        for (int ni = 0; ni < 4; ++ni)
          acc[mi][ni] = __builtin_amdgcn_mfma_f32_16x16x32_bf16(a[mi], b[ni],
                                                                acc[mi][ni], 0, 0, 0);
    }
  };

  for (int k0 = 0; k0 < K; k0 += 128) {
    // ---- tile k0 (set 0) ----
    __syncthreads();
#pragma unroll
    for (int i = 0; i < MI; ++i)
      *(uint4*)&As[(wave * (TM / 4) + i * 8 + srow) * 72 + scol] = a0[i];
#pragma unroll
    for (int i = 0; i < 4; ++i)
      *(uint4*)&Bs[(wave * 32 + i * 8 + srow) * 72 + scol] = b0[i];
    __syncthreads();
    if (k0 + 128 < K) {
#pragma unroll
      for (int i = 0; i < MI; ++i)
        a0[i] = *(const uint4*)(gA + (size_t)i * 8 * K + k0 + 128);
#pragma unroll
      for (int i = 0; i < 4; ++i)
        b0[i] = *(const uint4*)(gB + (size_t)i * 8 * K + k0 + 128);
    }
    compute();
    // ---- tile k0+64 (set 1) ----
    __syncthreads();
#pragma unroll
    for (int i = 0; i < MI; ++i)
      *(uint4*)&As[(wave * (TM / 4) + i * 8 + srow) * 72 + scol] = a1[i];
#pragma unroll
    for (int i = 0; i < 4; ++i)
      *(uint4*)&Bs[(wave * 32 + i * 8 + srow) * 72 + scol] = b1[i];
    __syncthreads();
    if (k0 + 192 < K) {
#pragma unroll
      for (int i = 0; i < MI; ++i)
        a1[i] = *(const uint4*)(gA + (size_t)i * 8 * K + k0 + 192);
#pragma unroll
      for (int i = 0; i < 4; ++i)
        b1[i] = *(const uint4*)(gB + (size_t)i * 8 * K + k0 + 192);
    }
    compute();
  }

  __syncthreads();  // all waves done reading As/Bs; reuse Bs as fp32 C-scratch
  float* Cs = (float*)Bs + wave * (16 * 68);

  if (mode == 0) {
    const float scale = 0.036084391824351615f;  // 768^-0.5
    int col0abs = cb * 128 + cw;
    int which = (col0abs >= 2 * DIM) ? 2 : ((col0abs >= DIM) ? 1 : 0);
    int h = (col0abs - which * DIM) >> 6;
    unsigned short* dstp = (which == 0) ? Qb : ((which == 1) ? Kb : V0);
    const float mul = (which == 0) ? scale : 1.f;
    float bvv[4];
#pragma unroll
    for (int ni = 0; ni < 4; ++ni) bvv[ni] = bias[col0abs + ni * 16 + ln16];
#pragma unroll
    for (int mi = 0; mi < MI; ++mi) {
#pragma unroll
      for (int ni = 0; ni < 4; ++ni)
#pragma unroll
        for (int r = 0; r < 4; ++r)
          Cs[(quad * 4 + r) * 68 + ni * 16 + ln16] = (acc[mi][ni][r] + bvv[ni]) * mul;
      __asm__ volatile("s_waitcnt lgkmcnt(0)" ::: "memory");  // wave-local region
      int token = rb * TM + rw + mi * 16 + ln16;
      int bb = token >> 12, nn = token & (NSEQ - 1);
      const float* src = &Cs[ln16 * 68 + quad * 16];
      float4 c0 = *(const float4*)(src + 0);
      float4 c1 = *(const float4*)(src + 4);
      float4 c2 = *(const float4*)(src + 8);
      float4 c3 = *(const float4*)(src + 12);
      unsigned short tmp[16];
      tmp[0] = f2bf(c0.x);  tmp[1] = f2bf(c0.y);  tmp[2] = f2bf(c0.z);  tmp[3] = f2bf(c0.w);
      tmp[4] = f2bf(c1.x);  tmp[5] = f2bf(c1.y);  tmp[6] = f2bf(c1.z);  tmp[7] = f2bf(c1.w);
      tmp[8] = f2bf(c2.x);  tmp[9] = f2bf(c2.y);  tmp[10] = f2bf(c2.z); tmp[11] = f2bf(c2.w);
      tmp[12] = f2bf(c3.x); tmp[13] = f2bf(c3.y); tmp[14] = f2bf(c3.z); tmp[15] = f2bf(c3.w);
      unsigned short* dp =
          dstp + ((size_t)(bb * HEADS + h) * NSEQ + nn) * DH + quad * 16;
      *(uint4*)&dp[0] = *(uint4*)&tmp[0];
      *(uint4*)&dp[8] = *(uint4*)&tmp[8];
      __asm__ volatile("s_waitcnt lgkmcnt(0)" ::: "memory");  // reads done before next mi
    }
  } else {
    float bvv[4];
#pragma unroll
    for (int ni = 0; ni < 4; ++ni) bvv[ni] = bias[cb * 128 + cw + ni * 16 + ln16];
#pragma unroll
    for (int mi = 0; mi < MI; ++mi) {
#pragma unroll
      for (int ni = 0; ni < 4; ++ni)
#pragma unroll
        for (int r = 0; r < 4; ++r)
          Cs[(quad * 4 + r) * 68 + ni * 16 + ln16] = acc[mi][ni][r] + bvv[ni];
      __asm__ volatile("s_waitcnt lgkmcnt(0)" ::: "memory");
      int token = rb * TM + rw + mi * 16 + ln16;
      const float* src = &Cs[ln16 * 68 + quad * 16];
      float4 c0 = *(const float4*)(src + 0);
      float4 c1 = *(const float4*)(src + 4);
      float4 c2 = *(const float4*)(src + 8);
      float4 c3 = *(const float4*)(src + 12);
      float* dp = outf + (size_t)token * N + cb * 128 + cw + quad * 16;
      *(float4*)(dp + 0) = c0;
      *(float4*)(dp + 4) = c1;
      *(float4*)(dp + 8) = c2;
      *(float4*)(dp + 12) = c3;
      __asm__ volatile("s_waitcnt lgkmcnt(0)" ::: "memory");
    }
  }
}

// ---------------------------------------------------------------------------
// MFMA flash attention (exact R6 version, 168 us): no-max softmax, denominator
// via ones-column; prefetch-pipelined staging, 2 barriers/tile; Ps handoff
// within-wave via s_waitcnt lgkmcnt(0).
// ---------------------------------------------------------------------------
__global__ __launch_bounds__(256) void attn_mfma3(
    const unsigned short* __restrict__ Qg, const unsigned short* __restrict__ Kg,
    const unsigned short* __restrict__ Vtg, unsigned short* __restrict__ ctxb) {
  __shared__ unsigned short Ks[64][72];     // [key][dh]
  __shared__ unsigned short Vts[64][72];    // [dh][key]
  __shared__ unsigned short Vones[16][72];  // row 0 = ones, rest 0
  __shared__ unsigned short Ps[4][32][72];

  int t = threadIdx.x;
  int wave = t >> 6, lane = t & 63;
  int ln16 = lane & 15, quad = lane >> 4;
  int bh = blockIdx.y;
  int q0 = blockIdx.x * 128;

  for (int i = t; i < 16 * 72; i += 256) {
    int r = i / 72, c = i % 72;
    Vones[r][c] = (r == 0 && c < 64) ? (unsigned short)0x3F80 : (unsigned short)0;
  }

  const unsigned short* Qp = Qg + ((size_t)bh * NSEQ + q0 + wave * 32) * DH;
  bf16x8 qf[2][2];
#pragma unroll
  for (int mi = 0; mi < 2; ++mi)
#pragma unroll
    for (int kh = 0; kh < 2; ++kh)
      qf[mi][kh] = *(const bf16x8*)(Qp + (size_t)(mi * 16 + ln16) * DH + kh * 32 + quad * 8);

  f32x4 O[2][5];
#pragma unroll
  for (int mi = 0; mi < 2; ++mi)
#pragma unroll
    for (int nt = 0; nt < 5; ++nt) O[mi][nt] = (f32x4){0.f, 0.f, 0.f, 0.f};

  const unsigned short* Kbase = Kg + (size_t)bh * NSEQ * DH;
  const unsigned short* Vbase = Vtg + (size_t)bh * DH * NSEQ;
  int srow = t >> 2, scol = (t & 3) << 4;

  uint4 kv0 = *(const uint4*)(Kbase + (size_t)srow * DH + scol);
  uint4 kv1 = *(const uint4*)(Kbase + (size_t)srow * DH + scol + 8);
  uint4 vv0 = *(const uint4*)(Vbase + (size_t)srow * NSEQ + scol);
  uint4 vv1 = *(const uint4*)(Vbase + (size_t)srow * NSEQ + scol + 8);

  for (int k0 = 0; k0 < NSEQ; k0 += 64) {
    __syncthreads();  // previous tile fully consumed (covers Vones init too)
    *(uint4*)&Ks[srow][scol] = kv0;
    *(uint4*)&Ks[srow][scol + 8] = kv1;
    *(uint4*)&Vts[srow][scol] = vv0;
    *(uint4*)&Vts[srow][scol + 8] = vv1;
    __syncthreads();
    if (k0 + 64 < NSEQ) {  // prefetch next tile during compute
      kv0 = *(const uint4*)(Kbase + (size_t)(k0 + 64 + srow) * DH + scol);
      kv1 = *(const uint4*)(Kbase + (size_t)(k0 + 64 + srow) * DH + scol + 8);
      vv0 = *(const uint4*)(Vbase + (size_t)srow * NSEQ + k0 + 64 + scol);
      vv1 = *(const uint4*)(Vbase + (size_t)srow * NSEQ + k0 + 64 + scol + 8);
    }

    // S = Q.K^T
    f32x4 S[2][4];
#pragma unroll
    for (int nt = 0; nt < 4; ++nt) {
      bf16x8 kb0 = *(const bf16x8*)&Ks[nt * 16 + ln16][quad * 8];
      bf16x8 kb1 = *(const bf16x8*)&Ks[nt * 16 + ln16][32 + quad * 8];
#pragma unroll
      for (int mi = 0; mi < 2; ++mi) {
        f32x4 s = (f32x4){0.f, 0.f, 0.f, 0.f};
        s = __builtin_amdgcn_mfma_f32_16x16x32_bf16(qf[mi][0], kb0, s, 0, 0, 0);
        s = __builtin_amdgcn_mfma_f32_16x16x32_bf16(qf[mi][1], kb1, s, 0, 0, 0);
        S[mi][nt] = s;
      }
    }

    // P = exp(S), C-layout -> LDS (per-wave region)
#pragma unroll
    for (int mi = 0; mi < 2; ++mi)
#pragma unroll
      for (int nt = 0; nt < 4; ++nt)
#pragma unroll
        for (int r = 0; r < 4; ++r)
          Ps[wave][mi * 16 + quad * 4 + r][nt * 16 + ln16] =
              f2bf(__expf(S[mi][nt][r]));
    __asm__ volatile("s_waitcnt lgkmcnt(0)" ::: "memory");

    // O += P.V (+ ones rows accumulate denominator)
    bf16x8 pa[2][2];
#pragma unroll
    for (int mi = 0; mi < 2; ++mi)
#pragma unroll
      for (int kh = 0; kh < 2; ++kh)
        pa[mi][kh] = *(const bf16x8*)&Ps[wave][mi * 16 + ln16][kh * 32 + quad * 8];
#pragma unroll
    for (int nt = 0; nt < 5; ++nt) {
      bf16x8 vb0, vb1;
      if (nt < 4) {
        vb0 = *(const bf16x8*)&Vts[nt * 16 + ln16][quad * 8];
        vb1 = *(const bf16x8*)&Vts[nt * 16 + ln16][32 + quad * 8];
      } else {
        vb0 = *(const bf16x8*)&Vones[ln16][quad * 8];
        vb1 = *(const bf16x8*)&Vones[ln16][32 + quad * 8];
      }
#pragma unroll
      for (int mi = 0; mi < 2; ++mi) {
        O[mi][nt] = __builtin_amdgcn_mfma_f32_16x16x32_bf16(pa[mi][0], vb0, O[mi][nt], 0, 0, 0);
        O[mi][nt] = __builtin_amdgcn_mfma_f32_16x16x32_bf16(pa[mi][1], vb1, O[mi][nt], 0, 0, 0);
      }
    }
  }

  int bb = bh / HEADS, h = bh % HEADS;
#pragma unroll
  for (int mi = 0; mi < 2; ++mi)
#pragma unroll
    for (int r = 0; r < 4; ++r) {
      float lsum = O[mi][4][r];
      lsum = __shfl(lsum, lane & 48);  // broadcast from ln16==0 of this quad
      float inv = 1.f / lsum;
      int token = q0 + wave * 32 + mi * 16 + quad * 4 + r;
      unsigned short* op = ctxb + ((size_t)(bb * NSEQ + token)) * DIM + h * DH;
#pragma unroll
      for (int nt = 0; nt < 4; ++nt)
        op[nt * 16 + ln16] = f2bf(O[mi][nt][r] * inv);
    }
}

// ---------------------------------------------------------------------------
extern "C" void kernel_launch(void* const* d_in, const int* in_sizes, int n_in,
                              void* d_out, int out_size, void* d_ws, size_t ws_size,
                              hipStream_t stream) {
  const float* x = (const float*)d_in[0];
  const float* w_qkv = (const float*)d_in[1];
  const float* b_qkv = (const float*)d_in[2];
  const float* w_out = (const float*)d_in[3];
  const float* b_out = (const float*)d_in[4];
  float* out = (float*)d_out;

  const size_t plane = (size_t)BH * NSEQ * DH;  // 6,291,456
  unsigned short* xb = (unsigned short*)d_ws;            // [8192][768]
  unsigned short* wqkvT = xb + plane;                    // [2304][768]
  unsigned short* woutT = wqkvT + (size_t)3 * DIM * DIM; // [768][768]
  unsigned short* Qb = woutT + (size_t)DIM * DIM;        // [bh][n][64]
  unsigned short* Kb = Qb + plane;                       // [bh][n][64]
  unsigned short* V0 = Kb + plane;                       // [bh][n][64]
  unsigned short* Vtb = V0 + plane;                      // [bh][64][n]
  unsigned short* ctxb = Vtb + plane;                    // [8192][768]

  cvt_bf16<<<dim3((int)(plane / 2048)), 256, 0, stream>>>(x, xb, (int)plane);
  transpose_cvt<<<dim3(3 * DIM / 32, DIM / 32), 256, 0, stream>>>(w_qkv, wqkvT, DIM, 3 * DIM);
  transpose_cvt<<<dim3(DIM / 32, DIM / 32), 256, 0, stream>>>(w_out, woutT, DIM, DIM);

  gemm_bt2<128><<<dim3(3 * DIM / 128, BATCH * NSEQ / 128), 256, 0, stream>>>(
      xb, wqkvT, b_qkv, nullptr, Qb, Kb, V0, BATCH * NSEQ, 3 * DIM, DIM, 0);

  vtrans<<<dim3(NSEQ / 64, BH), 256, 0, stream>>>(V0, Vtb);

  attn_mfma3<<<dim3(NSEQ / 128, BH), 256, 0, stream>>>(Qb, Kb, Vtb, ctxb);

  gemm_bt2<64><<<dim3(DIM / 128, BATCH * NSEQ / 64), 256, 0, stream>>>(
      ctxb, woutT, b_out, out, nullptr, nullptr, nullptr, BATCH * NSEQ, DIM, DIM, 1);
}